// Round 5
// baseline (463.191 us; speedup 1.0000x reference)
//
#include <hip/hip_runtime.h>
#include <math.h>

#define CCH   256
#define NPIX  4096
#define BATCH 4

typedef __attribute__((ext_vector_type(8))) short s16x8;
typedef __attribute__((ext_vector_type(4))) float f32x4;

__device__ __forceinline__ unsigned short f2bf(float f) {
    unsigned int u = __float_as_uint(f);
    u += 0x7fff + ((u >> 16) & 1);          // RNE; values are finite
    return (unsigned short)(u >> 16);
}
__device__ __forceinline__ float bf2f(unsigned short h) {
    return __uint_as_float(((unsigned int)h) << 16);
}

// q/k frag (16x16x32 A/B layout), element for (pixel n, dim d):
//   tile = n>>4, lane = (d>>3)*16 + (n&15), elem = d&7
__device__ __forceinline__ size_t qk_addr(int b, int n, int d) {
    return ((((size_t)b * 256 + (n >> 4)) * 64 + ((d >> 3) << 4) + (n & 15)) << 3) + (d & 7);
}
// v frag: standard A-layout for PV; k = j (32-step), m = c (16-tile):
//   tile = (b, j64, c-tile, jj-half), lane = ((j&31)>>3)*16 + (c&15), elem = j&7
__device__ __forceinline__ size_t v_addr(int b, int j, int c) {
    return ((((((size_t)b * 64 + (j >> 6)) * 16 + (c >> 4)) * 2 + ((j >> 5) & 1)) * 64
            + (((j >> 3) & 3) << 4) + (c & 15)) << 3) + (j & 7);
}

// ---------------- W -> A-frag bf16 (hi/lo for q,k; hi for v), once ----------------
// 20 blocks x 64 thr; block rt: tiles 0,1=q (pre-scaled log2e), 2,3=k, 4..19=v
__global__ __launch_bounds__(64) void wcast_kernel(
    const float* __restrict__ Wq, const float* __restrict__ bq,
    const float* __restrict__ Wk, const float* __restrict__ bk,
    const float* __restrict__ Wv, const float* __restrict__ bv,
    unsigned short* __restrict__ wfh, unsigned short* __restrict__ wfl,
    float* __restrict__ bias_ws)
{
    const int rt = blockIdx.x;
    const int lane = threadIdx.x, l15 = lane & 15, quad = lane >> 4;
    const float *Ws, *bs; int roff; float scale = 1.0f;
    if (rt < 2)      { Ws = Wq; bs = bq; roff = rt * 16;      scale = 1.44269504f; }
    else if (rt < 4) { Ws = Wk; bs = bk; roff = (rt - 2) * 16; }
    else             { Ws = Wv; bs = bv; roff = (rt - 4) * 16; }

    const float* wrow = Ws + (size_t)(roff + l15) * CCH + quad * 8;
    for (int kb = 0; kb < 8; ++kb) {
        s16x8 h, l;
        #pragma unroll
        for (int d = 0; d < 8; ++d) {
            float wv = wrow[kb * 32 + d] * scale;
            unsigned short hh = f2bf(wv);
            h[d] = (short)hh;
            l[d] = (short)f2bf(wv - bf2f(hh));
        }
        *(s16x8*)&wfh[(((size_t)rt * 8 + kb) * 64 + lane) * 8] = h;
        if (rt < 4) *(s16x8*)&wfl[(((size_t)rt * 8 + kb) * 64 + lane) * 8] = l;
    }
    if (lane < 16) bias_ws[rt * 16 + lane] = bs[roff + lane] * scale;
}

// ---------------- fused cast+projection ----------------
// 512 blocks x 4 waves: wave = (rh 0..1, np 0..1). Wave: pixel tile nt = bx*2+np,
// builds x hi/lo B-frags in-register once, reuses across its 10 row-tiles.
__global__ __launch_bounds__(256, 2) void proj_kernel(
    const float* __restrict__ x,
    const unsigned short* __restrict__ wfh, const unsigned short* __restrict__ wfl,
    const float* __restrict__ bias_ws,
    unsigned short* __restrict__ q_hi, unsigned short* __restrict__ q_lo,
    unsigned short* __restrict__ k_hi, unsigned short* __restrict__ k_lo,
    unsigned short* __restrict__ v_frag)
{
    const int t = threadIdx.x;
    const int w = t >> 6, lane = t & 63, l15 = lane & 15, quad = lane >> 4;
    const int rh = w >> 1, np = w & 1;
    const int b = blockIdx.y;
    const int nt = blockIdx.x * 2 + np;

    // build x B-frags (hi/lo) for this 16-pixel tile
    const float* xb = x + (size_t)b * CCH * NPIX + nt * 16 + l15;
    s16x8 xh[8], xl[8];
    #pragma unroll
    for (int kb = 0; kb < 8; ++kb) {
        s16x8 vh, vl;
        #pragma unroll
        for (int d = 0; d < 8; ++d) {
            float xv = xb[(size_t)(kb * 32 + quad * 8 + d) * NPIX];
            unsigned short h = f2bf(xv);
            vh[d] = (short)h;
            vl[d] = (short)f2bf(xv - bf2f(h));
        }
        xh[kb] = vh; xl[kb] = vl;
    }

    const int n = nt * 16 + l15;
    #pragma unroll 1
    for (int tt = 0; tt < 10; ++tt) {
        const int rt = rh * 10 + tt;
        f32x4 acc = {0.f, 0.f, 0.f, 0.f};
        if (rt < 4) {
            #pragma unroll
            for (int kb = 0; kb < 8; ++kb) {
                s16x8 ah = *(const s16x8*)&wfh[(((size_t)rt * 8 + kb) * 64 + lane) * 8];
                s16x8 al = *(const s16x8*)&wfl[(((size_t)rt * 8 + kb) * 64 + lane) * 8];
                acc = __builtin_amdgcn_mfma_f32_16x16x32_bf16(ah, xl[kb], acc, 0, 0, 0);
                acc = __builtin_amdgcn_mfma_f32_16x16x32_bf16(al, xh[kb], acc, 0, 0, 0);
                acc = __builtin_amdgcn_mfma_f32_16x16x32_bf16(ah, xh[kb], acc, 0, 0, 0);
            }
        } else {
            #pragma unroll
            for (int kb = 0; kb < 8; ++kb) {
                s16x8 ah = *(const s16x8*)&wfh[(((size_t)rt * 8 + kb) * 64 + lane) * 8];
                acc = __builtin_amdgcn_mfma_f32_16x16x32_bf16(ah, xh[kb], acc, 0, 0, 0);
            }
        }
        #pragma unroll
        for (int rr = 0; rr < 4; ++rr) {
            const int rloc = quad * 4 + rr;
            const float val = acc[rr] + bias_ws[rt * 16 + rloc];
            if (rt < 2) {               // q rows 0..31
                unsigned short h = f2bf(val);
                const size_t a = qk_addr(b, n, rt * 16 + rloc);
                q_hi[a] = h; q_lo[a] = f2bf(val - bf2f(h));
            } else if (rt < 4) {        // k rows 0..31
                unsigned short h = f2bf(val);
                const size_t a = qk_addr(b, n, (rt - 2) * 16 + rloc);
                k_hi[a] = h; k_lo[a] = f2bf(val - bf2f(h));
            } else {                    // v rows 0..255
                v_frag[v_addr(b, n, (rt - 4) * 16 + rloc)] = f2bf(val);
            }
        }
    }
}

// ---------------- flash attention: 64c x 64i waves, P via LDS ----------------
// 256 blocks (1/CU) x 8 waves = (jh 0..1, ch 0..3). Wave: 64 channels (ch quarter),
// 64 i (4 tiles), j-half jh (32 iters of 64 j). Sc^T quarter per ch-wave, shared
// through LDS in B-frag layout; PV reads all 8 P-frags + own V quarter.
__global__ __launch_bounds__(512, 2) void attn_kernel(
    const unsigned short* __restrict__ q_hi, const unsigned short* __restrict__ q_lo,
    const unsigned short* __restrict__ k_hi, const unsigned short* __restrict__ k_lo,
    const unsigned short* __restrict__ v_frag,
    const float* __restrict__ x, float* __restrict__ out)
{
    __shared__ unsigned short p_lds[2][2][8][512];   // [jh][dbuf][frag][lane*8] = 32 KB
    __shared__ float comb[2][4][64][34];             // epilogue partials, ~70 KB
    __shared__ float lds_l[2][4][16];

    const int t = threadIdx.x;
    const int w = t >> 6, lane = t & 63, l15 = lane & 15, quad = lane >> 4;
    const int jh = w >> 2, ch = w & 3;

    const int f = blockIdx.x;                 // 0..255; XCD-pair per batch
    const int xcd = f & 7;
    const int b = xcd >> 1;
    const int ib = ((xcd & 1) << 5) + (f >> 3);   // i-block 0..63 (64 pixels)

    // Q B-frags (hi/lo) for 4 i-tiles
    s16x8 qfh[4], qfl[4];
    #pragma unroll
    for (int it = 0; it < 4; ++it) {
        const size_t qo = ((size_t)b * 256 + ib * 4 + it) * 512 + (size_t)lane * 8;
        qfh[it] = *(const s16x8*)(q_hi + qo);
        qfl[it] = *(const s16x8*)(q_lo + qo);
    }

    const s16x8 ones = { (short)0x3F80, (short)0x3F80, (short)0x3F80, (short)0x3F80,
                         (short)0x3F80, (short)0x3F80, (short)0x3F80, (short)0x3F80 };

    f32x4 acc[16];                            // [ct][it]
    #pragma unroll
    for (int i = 0; i < 16; ++i) acc[i] = (f32x4){0.f, 0.f, 0.f, 0.f};
    f32x4 lacc = {0.f, 0.f, 0.f, 0.f};

    const unsigned short* khb = k_hi + (size_t)b * 131072 + (size_t)lane * 8;
    const unsigned short* klb = k_lo + (size_t)b * 131072 + (size_t)lane * 8;
    const unsigned short* vb  = v_frag + (size_t)b * 1048576 + (size_t)lane * 8;

    const int prow = ((ch & 1) << 1) + (quad >> 1);      // P-write row within frag
    const int pcol = ((quad & 1) << 2);                  // elem offset (4 ushorts)
    const int pfrag_jj = ch >> 1;

    #pragma unroll 1
    for (int j5 = 0; j5 < 32; ++j5) {
        const int jt = jh * 32 + j5;          // 64-j tile
        const int buf = j5 & 1;
        // ---- S^T quarter: K tile (jt*4+ch), 4 i-tiles x 3-term ----
        const size_t ko = (size_t)(jt * 4 + ch) * 512;
        const s16x8 kfh = *(const s16x8*)(khb + ko);
        const s16x8 kfl = *(const s16x8*)(klb + ko);
        #pragma unroll
        for (int it = 0; it < 4; ++it) {
            f32x4 a0 = __builtin_amdgcn_mfma_f32_16x16x32_bf16(kfh, qfl[it], (f32x4){0.f,0.f,0.f,0.f}, 0, 0, 0);
            a0 = __builtin_amdgcn_mfma_f32_16x16x32_bf16(kfl, qfh[it], a0, 0, 0, 0);
            a0 = __builtin_amdgcn_mfma_f32_16x16x32_bf16(kfh, qfh[it], a0, 0, 0, 0);
            // exp2 + pack 4 values (rr 0..3) -> 2 dwords -> one ds_write_b64
            unsigned int u0 = __float_as_uint(__builtin_exp2f(a0[0])) + 0x8000u;
            unsigned int u1 = __float_as_uint(__builtin_exp2f(a0[1])) + 0x8000u;
            unsigned int u2 = __float_as_uint(__builtin_exp2f(a0[2])) + 0x8000u;
            unsigned int u3 = __float_as_uint(__builtin_exp2f(a0[3])) + 0x8000u;
            uint2 pv;
            pv.x = __builtin_amdgcn_perm(u1, u0, 0x07060302u);
            pv.y = __builtin_amdgcn_perm(u3, u2, 0x07060302u);
            *(uint2*)&p_lds[jh][buf][it * 2 + pfrag_jj][(prow * 16 + l15) * 8 + pcol] = pv;
        }
        __syncthreads();
        // ---- read all 8 P B-frags ----
        s16x8 pf[8];
        #pragma unroll
        for (int ff = 0; ff < 8; ++ff)
            pf[ff] = *(const s16x8*)&p_lds[jh][buf][ff][lane * 8];
        // ---- denominator partial (i-tile = ch) ----
        lacc = __builtin_amdgcn_mfma_f32_16x16x32_bf16(ones, pf[ch * 2 + 0], lacc, 0, 0, 0);
        lacc = __builtin_amdgcn_mfma_f32_16x16x32_bf16(ones, pf[ch * 2 + 1], lacc, 0, 0, 0);
        // ---- PV: V quarter (4 c-tiles) x 4 i-tiles x 2 jj ----
        #pragma unroll
        for (int ct = 0; ct < 4; ++ct) {
            const size_t vo = (((size_t)jt * 16 + ch * 4 + ct) * 2) * 512;
            const s16x8 v0 = *(const s16x8*)(vb + vo);
            const s16x8 v1 = *(const s16x8*)(vb + vo + 512);
            #pragma unroll
            for (int it = 0; it < 4; ++it) {
                acc[ct * 4 + it] = __builtin_amdgcn_mfma_f32_16x16x32_bf16(v0, pf[it * 2 + 0], acc[ct * 4 + it], 0, 0, 0);
                acc[ct * 4 + it] = __builtin_amdgcn_mfma_f32_16x16x32_bf16(v1, pf[it * 2 + 1], acc[ct * 4 + it], 0, 0, 0);
            }
        }
    }

    // ---- epilogue: publish l partials + cross-jh acc combine, both halves store ----
    if (lane < 16) lds_l[jh][ch][lane] = lacc[0];
    {
        const int jo = 1 - jh;                // publish the it-pair we don't own
        #pragma unroll
        for (int ct = 0; ct < 4; ++ct)
            #pragma unroll
            for (int itp = 0; itp < 2; ++itp)
                *(f32x4*)&comb[jo][ch][lane][ct * 8 + itp * 4] = acc[ct * 4 + jo * 2 + itp];
    }
    __syncthreads();
    float linv[2];
    #pragma unroll
    for (int itp = 0; itp < 2; ++itp) {
        const int it = jh * 2 + itp;
        linv[itp] = 1.f / (lds_l[0][it][l15] + lds_l[1][it][l15]);
    }
    #pragma unroll
    for (int ct = 0; ct < 4; ++ct) {
        #pragma unroll
        for (int itp = 0; itp < 2; ++itp) {
            const int it = jh * 2 + itp;
            f32x4 a = acc[ct * 4 + it];
            a += *(const f32x4*)&comb[jh][ch][lane][ct * 8 + itp * 4];
            const int ibase = (ib * 4 + it) * 16 + l15;
            #pragma unroll
            for (int rr = 0; rr < 4; ++rr) {
                const int c = ch * 64 + ct * 16 + quad * 4 + rr;
                const size_t idx = ((size_t)b * CCH + c) * NPIX + ibase;
                out[idx] = a[rr] * linv[itp] + x[idx];
            }
        }
    }
}

extern "C" void kernel_launch(void* const* d_in, const int* in_sizes, int n_in,
                              void* d_out, int out_size, void* d_ws, size_t ws_size,
                              hipStream_t stream) {
    const float* x  = (const float*)d_in[0];
    const float* Wq = (const float*)d_in[1];
    const float* bq = (const float*)d_in[2];
    const float* Wk = (const float*)d_in[3];
    const float* bk = (const float*)d_in[4];
    const float* Wv = (const float*)d_in[5];
    const float* bv = (const float*)d_in[6];
    float* out = (float*)d_out;

    unsigned short* ws = (unsigned short*)d_ws;
    unsigned short* q_hi   = ws;                 //   524,288
    unsigned short* q_lo   = ws + 524288;        //   524,288
    unsigned short* k_hi   = ws + 1048576;       //   524,288
    unsigned short* k_lo   = ws + 1572864;       //   524,288
    unsigned short* v_frag = ws + 2097152;       // 4,194,304
    unsigned short* wfh    = ws + 6291456;       //    81,920
    unsigned short* wfl    = ws + 6373376;       //    16,384
    float*          bias_ws = (float*)(ws + 6389760);  // 320 floats (~12.8 MB total)

    wcast_kernel<<<20, 64, 0, stream>>>(Wq, bq, Wk, bk, Wv, bv, wfh, wfl, bias_ws);
    proj_kernel<<<dim3(128, BATCH), 256, 0, stream>>>(x, wfh, wfl, bias_ws,
                                                      q_hi, q_lo, k_hi, k_lo, v_frag);
    attn_kernel<<<256, 512, 0, stream>>>(q_hi, q_lo, k_hi, k_lo, v_frag, x, out);
}

// Round 6
// 249.968 us; speedup vs baseline: 1.8530x; 1.8530x over previous
//
#include <hip/hip_runtime.h>
#include <math.h>

#define CCH   256
#define NPIX  4096
#define BATCH 4

typedef __attribute__((ext_vector_type(8))) short s16x8;
typedef __attribute__((ext_vector_type(4))) float f32x4;

__device__ __forceinline__ unsigned short f2bf(float f) {
    unsigned int u = __float_as_uint(f);
    u += 0x7fff + ((u >> 16) & 1);          // RNE; values are finite
    return (unsigned short)(u >> 16);
}
__device__ __forceinline__ float bf2f(unsigned short h) {
    return __uint_as_float(((unsigned int)h) << 16);
}

// q/k frag (16x16x32 A/B layout), element for (pixel n, dim d):
//   tile = n>>4, lane = (d>>3)*16 + (n&15), elem = d&7
__device__ __forceinline__ size_t qk_addr(int b, int n, int d) {
    return ((((size_t)b * 256 + (n >> 4)) * 64 + ((d >> 3) << 4) + (n & 15)) << 3) + (d & 7);
}
// v frag: standard A-layout for PV; k = j (32-step), m = c (16-tile):
//   tile = (b, j64, c-tile, jj-half), lane = ((j&31)>>3)*16 + (c&15), elem = j&7
__device__ __forceinline__ size_t v_addr(int b, int j, int c) {
    return ((((((size_t)b * 64 + (j >> 6)) * 16 + (c >> 4)) * 2 + ((j >> 5) & 1)) * 64
            + (((j >> 3) & 3) << 4) + (c & 15)) << 3) + (j & 7);
}

// ---------------- W -> A-frag bf16 (hi/lo for q,k; hi for v), once ----------------
__global__ __launch_bounds__(64) void wcast_kernel(
    const float* __restrict__ Wq, const float* __restrict__ bq,
    const float* __restrict__ Wk, const float* __restrict__ bk,
    const float* __restrict__ Wv, const float* __restrict__ bv,
    unsigned short* __restrict__ wfh, unsigned short* __restrict__ wfl,
    float* __restrict__ bias_ws)
{
    const int rt = blockIdx.x;
    const int lane = threadIdx.x, l15 = lane & 15, quad = lane >> 4;
    const float *Ws, *bs; int roff; float scale = 1.0f;
    if (rt < 2)      { Ws = Wq; bs = bq; roff = rt * 16;      scale = 1.44269504f; }
    else if (rt < 4) { Ws = Wk; bs = bk; roff = (rt - 2) * 16; }
    else             { Ws = Wv; bs = bv; roff = (rt - 4) * 16; }

    const float* wrow = Ws + (size_t)(roff + l15) * CCH + quad * 8;
    for (int kb = 0; kb < 8; ++kb) {
        s16x8 h, l;
        #pragma unroll
        for (int d = 0; d < 8; ++d) {
            float wv = wrow[kb * 32 + d] * scale;
            unsigned short hh = f2bf(wv);
            h[d] = (short)hh;
            l[d] = (short)f2bf(wv - bf2f(hh));
        }
        *(s16x8*)&wfh[(((size_t)rt * 8 + kb) * 64 + lane) * 8] = h;
        if (rt < 4) *(s16x8*)&wfl[(((size_t)rt * 8 + kb) * 64 + lane) * 8] = l;
    }
    if (lane < 16) bias_ws[rt * 16 + lane] = bs[roff + lane] * scale;
}

// ---------------- fused cast+projection ----------------
// 1024 blocks (b, nt) x 4 waves (rh). Wave: builds x hi/lo B-frags in-register,
// computes 5 row-tiles (rh*5..rh*5+4). 16 waves/CU.
__global__ __launch_bounds__(256, 4) void proj_kernel(
    const float* __restrict__ x,
    const unsigned short* __restrict__ wfh, const unsigned short* __restrict__ wfl,
    const float* __restrict__ bias_ws,
    unsigned short* __restrict__ q_hi, unsigned short* __restrict__ q_lo,
    unsigned short* __restrict__ k_hi, unsigned short* __restrict__ k_lo,
    unsigned short* __restrict__ v_frag)
{
    const int t = threadIdx.x;
    const int rh = t >> 6, lane = t & 63, l15 = lane & 15, quad = lane >> 4;
    const int b = blockIdx.y;
    const int nt = blockIdx.x;

    // build x B-frags (hi/lo) for this 16-pixel tile (all 4 waves: L1-shared)
    const float* xb = x + (size_t)b * CCH * NPIX + nt * 16 + l15;
    s16x8 xh[8], xl[8];
    #pragma unroll
    for (int kb = 0; kb < 8; ++kb) {
        s16x8 vh, vl;
        #pragma unroll
        for (int d = 0; d < 8; ++d) {
            float xv = xb[(size_t)(kb * 32 + quad * 8 + d) * NPIX];
            unsigned short h = f2bf(xv);
            vh[d] = (short)h;
            vl[d] = (short)f2bf(xv - bf2f(h));
        }
        xh[kb] = vh; xl[kb] = vl;
    }

    const int n = nt * 16 + l15;
    #pragma unroll 1
    for (int tt = 0; tt < 5; ++tt) {
        const int rt = rh * 5 + tt;
        if (rt < 4) {
            f32x4 acc0 = {0.f, 0.f, 0.f, 0.f};   // split chains for dep latency
            f32x4 acc1 = {0.f, 0.f, 0.f, 0.f};
            #pragma unroll
            for (int kb = 0; kb < 8; ++kb) {
                s16x8 ah = *(const s16x8*)&wfh[(((size_t)rt * 8 + kb) * 64 + lane) * 8];
                s16x8 al = *(const s16x8*)&wfl[(((size_t)rt * 8 + kb) * 64 + lane) * 8];
                acc0 = __builtin_amdgcn_mfma_f32_16x16x32_bf16(ah, xh[kb], acc0, 0, 0, 0);
                acc1 = __builtin_amdgcn_mfma_f32_16x16x32_bf16(ah, xl[kb], acc1, 0, 0, 0);
                acc1 = __builtin_amdgcn_mfma_f32_16x16x32_bf16(al, xh[kb], acc1, 0, 0, 0);
            }
            #pragma unroll
            for (int rr = 0; rr < 4; ++rr) {
                const int rloc = quad * 4 + rr;
                const float val = acc0[rr] + acc1[rr] + bias_ws[rt * 16 + rloc];
                unsigned short h = f2bf(val);
                unsigned short l = f2bf(val - bf2f(h));
                if (rt < 2) {
                    const size_t a = qk_addr(b, n, rt * 16 + rloc);
                    q_hi[a] = h; q_lo[a] = l;
                } else {
                    const size_t a = qk_addr(b, n, (rt - 2) * 16 + rloc);
                    k_hi[a] = h; k_lo[a] = l;
                }
            }
        } else {
            f32x4 acc = {0.f, 0.f, 0.f, 0.f};
            #pragma unroll
            for (int kb = 0; kb < 8; ++kb) {
                s16x8 ah = *(const s16x8*)&wfh[(((size_t)rt * 8 + kb) * 64 + lane) * 8];
                acc = __builtin_amdgcn_mfma_f32_16x16x32_bf16(ah, xh[kb], acc, 0, 0, 0);
            }
            #pragma unroll
            for (int rr = 0; rr < 4; ++rr) {
                const int rloc = quad * 4 + rr;
                const float val = acc[rr] + bias_ws[rt * 16 + rloc];
                v_frag[v_addr(b, n, (rt - 4) * 16 + rloc)] = f2bf(val);
            }
        }
    }
}

// ---------------- flash attention: 64c x 32i waves, P via LDS ----------------
// 512 blocks (2/CU, same batch per CU) x 8 waves = (jh 0..1, ch 0..3).
// Wave: 64 channels (ch quarter), 2 i-tiles, j-half jh (32 iters of 64 j).
__global__ __launch_bounds__(512, 4) void attn_kernel(
    const unsigned short* __restrict__ q_hi, const unsigned short* __restrict__ q_lo,
    const unsigned short* __restrict__ k_hi, const unsigned short* __restrict__ k_lo,
    const unsigned short* __restrict__ v_frag,
    const float* __restrict__ x, float* __restrict__ out)
{
    __shared__ unsigned short p_lds[2][2][4][512];   // [jh][dbuf][frag][lane*8] = 16 KB
    __shared__ float comb[2][4][64][20];             // [jh_src][ch][lane][16(+4 pad)] = 40 KB
    __shared__ float lds_l[2][2][16];

    const int t = threadIdx.x;
    const int w = t >> 6, lane = t & 63, l15 = lane & 15, quad = lane >> 4;
    const int jh = w >> 2, ch = w & 3;

    const int f = blockIdx.x;                 // 0..511; XCD-pair per batch
    const int xcd = f & 7;
    const int b = xcd >> 1;
    const int ib = ((xcd & 1) << 6) + (f >> 3);   // i-block 0..127 (32 pixels)

    // Q B-frags (hi/lo) for 2 i-tiles
    s16x8 qfh[2], qfl[2];
    #pragma unroll
    for (int it = 0; it < 2; ++it) {
        const size_t qo = ((size_t)b * 256 + ib * 2 + it) * 512 + (size_t)lane * 8;
        qfh[it] = *(const s16x8*)(q_hi + qo);
        qfl[it] = *(const s16x8*)(q_lo + qo);
    }

    const s16x8 ones = { (short)0x3F80, (short)0x3F80, (short)0x3F80, (short)0x3F80,
                         (short)0x3F80, (short)0x3F80, (short)0x3F80, (short)0x3F80 };

    f32x4 acc[8];                             // [ct][it]
    #pragma unroll
    for (int i = 0; i < 8; ++i) acc[i] = (f32x4){0.f, 0.f, 0.f, 0.f};
    f32x4 lacc = {0.f, 0.f, 0.f, 0.f};

    const unsigned short* khb = k_hi + (size_t)b * 131072 + (size_t)lane * 8;
    const unsigned short* klb = k_lo + (size_t)b * 131072 + (size_t)lane * 8;
    const unsigned short* vb  = v_frag + (size_t)b * 1048576 + (size_t)lane * 8;

    const int prow = ((ch & 1) << 1) + (quad >> 1);      // P-write row within frag
    const int pcol = ((quad & 1) << 2);                  // elem offset (4 ushorts)
    const int pfrag_jj = ch >> 1;

    #pragma unroll 1
    for (int j5 = 0; j5 < 32; ++j5) {
        const int jt = jh * 32 + j5;          // 64-j tile
        const int buf = j5 & 1;
        // ---- S^T quarter: K tile (jt*4+ch), 2 i-tiles x 3-term ----
        const size_t ko = (size_t)(jt * 4 + ch) * 512;
        const s16x8 kfh = *(const s16x8*)(khb + ko);
        const s16x8 kfl = *(const s16x8*)(klb + ko);
        #pragma unroll
        for (int it = 0; it < 2; ++it) {
            f32x4 a0 = __builtin_amdgcn_mfma_f32_16x16x32_bf16(kfh, qfl[it], (f32x4){0.f,0.f,0.f,0.f}, 0, 0, 0);
            a0 = __builtin_amdgcn_mfma_f32_16x16x32_bf16(kfl, qfh[it], a0, 0, 0, 0);
            a0 = __builtin_amdgcn_mfma_f32_16x16x32_bf16(kfh, qfh[it], a0, 0, 0, 0);
            unsigned int u0 = __float_as_uint(__builtin_exp2f(a0[0])) + 0x8000u;
            unsigned int u1 = __float_as_uint(__builtin_exp2f(a0[1])) + 0x8000u;
            unsigned int u2 = __float_as_uint(__builtin_exp2f(a0[2])) + 0x8000u;
            unsigned int u3 = __float_as_uint(__builtin_exp2f(a0[3])) + 0x8000u;
            uint2 pv;
            pv.x = __builtin_amdgcn_perm(u1, u0, 0x07060302u);
            pv.y = __builtin_amdgcn_perm(u3, u2, 0x07060302u);
            *(uint2*)&p_lds[jh][buf][it * 2 + pfrag_jj][(prow * 16 + l15) * 8 + pcol] = pv;
        }
        __syncthreads();
        // ---- read 4 P B-frags (2 it x 2 jj) ----
        s16x8 pf[4];
        #pragma unroll
        for (int ff = 0; ff < 4; ++ff)
            pf[ff] = *(const s16x8*)&p_lds[jh][buf][ff][lane * 8];
        // ---- denominator partials: ch0 -> it0, ch1 -> it1 ----
        if (ch < 2) {
            lacc = __builtin_amdgcn_mfma_f32_16x16x32_bf16(ones, pf[ch * 2 + 0], lacc, 0, 0, 0);
            lacc = __builtin_amdgcn_mfma_f32_16x16x32_bf16(ones, pf[ch * 2 + 1], lacc, 0, 0, 0);
        }
        // ---- PV: V quarter (4 c-tiles) x 2 i-tiles x 2 jj ----
        #pragma unroll
        for (int ct = 0; ct < 4; ++ct) {
            const size_t vo = (((size_t)jt * 16 + ch * 4 + ct) * 2) * 512;
            const s16x8 v0 = *(const s16x8*)(vb + vo);
            const s16x8 v1 = *(const s16x8*)(vb + vo + 512);
            #pragma unroll
            for (int it = 0; it < 2; ++it) {
                acc[ct * 2 + it] = __builtin_amdgcn_mfma_f32_16x16x32_bf16(v0, pf[it * 2 + 0], acc[ct * 2 + it], 0, 0, 0);
                acc[ct * 2 + it] = __builtin_amdgcn_mfma_f32_16x16x32_bf16(v1, pf[it * 2 + 1], acc[ct * 2 + it], 0, 0, 0);
            }
        }
    }

    // ---- epilogue: publish l + the it we don't keep; combine; store ----
    if (ch < 2 && lane < 16) lds_l[jh][ch][lane] = lacc[0];
    {
        const int jo = 1 - jh;                // publish the it we don't own (own it = jh)
        #pragma unroll
        for (int ct = 0; ct < 4; ++ct)
            *(f32x4*)&comb[jh][ch][lane][ct * 4] = acc[ct * 2 + jo];
    }
    __syncthreads();
    const float linv = 1.f / (lds_l[0][jh][l15] + lds_l[1][jh][l15]);
    const int ibase = (ib * 2 + jh) * 16 + l15;
    #pragma unroll
    for (int ct = 0; ct < 4; ++ct) {
        f32x4 a = acc[ct * 2 + jh];
        a += *(const f32x4*)&comb[1 - jh][ch][lane][ct * 4];
        #pragma unroll
        for (int rr = 0; rr < 4; ++rr) {
            const int c = ch * 64 + ct * 16 + quad * 4 + rr;
            const size_t idx = ((size_t)b * CCH + c) * NPIX + ibase;
            out[idx] = a[rr] * linv + x[idx];
        }
    }
}

extern "C" void kernel_launch(void* const* d_in, const int* in_sizes, int n_in,
                              void* d_out, int out_size, void* d_ws, size_t ws_size,
                              hipStream_t stream) {
    const float* x  = (const float*)d_in[0];
    const float* Wq = (const float*)d_in[1];
    const float* bq = (const float*)d_in[2];
    const float* Wk = (const float*)d_in[3];
    const float* bk = (const float*)d_in[4];
    const float* Wv = (const float*)d_in[5];
    const float* bv = (const float*)d_in[6];
    float* out = (float*)d_out;

    unsigned short* ws = (unsigned short*)d_ws;
    unsigned short* q_hi   = ws;                 //   524,288
    unsigned short* q_lo   = ws + 524288;        //   524,288
    unsigned short* k_hi   = ws + 1048576;       //   524,288
    unsigned short* k_lo   = ws + 1572864;       //   524,288
    unsigned short* v_frag = ws + 2097152;       // 4,194,304
    unsigned short* wfh    = ws + 6291456;       //    81,920
    unsigned short* wfl    = ws + 6373376;       //    16,384
    float*          bias_ws = (float*)(ws + 6389760);  // 320 floats (~12.8 MB total)

    wcast_kernel<<<20, 64, 0, stream>>>(Wq, bq, Wk, bk, Wv, bv, wfh, wfl, bias_ws);
    proj_kernel<<<dim3(256, BATCH), 256, 0, stream>>>(x, wfh, wfl, bias_ws,
                                                      q_hi, q_lo, k_hi, k_lo, v_frag);
    attn_kernel<<<512, 512, 0, stream>>>(q_hi, q_lo, k_hi, k_lo, v_frag, x, out);
}

// Round 7
// 180.299 us; speedup vs baseline: 2.5690x; 1.3864x over previous
//
#include <hip/hip_runtime.h>
#include <math.h>

#define CCH   256
#define NPIX  4096
#define BATCH 4

typedef __attribute__((ext_vector_type(8))) short s16x8;
typedef __attribute__((ext_vector_type(4))) float f32x4;

__device__ __forceinline__ unsigned short f2bf(float f) {
    unsigned int u = __float_as_uint(f);
    u += 0x7fff + ((u >> 16) & 1);          // RNE; values are finite
    return (unsigned short)(u >> 16);
}
__device__ __forceinline__ float bf2f(unsigned short h) {
    return __uint_as_float(((unsigned int)h) << 16);
}

// q/k frag (16x16x32 A/B layout), element for (pixel n, dim d):
//   tile = n>>4, lane = (d>>3)*16 + (n&15), elem = d&7
__device__ __forceinline__ size_t qk_addr(int b, int n, int d) {
    return ((((size_t)b * 256 + (n >> 4)) * 64 + ((d >> 3) << 4) + (n & 15)) << 3) + (d & 7);
}
// v frag: standard A-layout for PV; k = j (32-step), m = c (16-tile):
//   tile = (b, j64, c-tile, jj-half), lane = ((j&31)>>3)*16 + (c&15), elem = j&7
__device__ __forceinline__ size_t v_addr(int b, int j, int c) {
    return ((((((size_t)b * 64 + (j >> 6)) * 16 + (c >> 4)) * 2 + ((j >> 5) & 1)) * 64
            + (((j >> 3) & 3) << 4) + (c & 15)) << 3) + (j & 7);
}

// ---------------- W -> A-frag bf16 (hi/lo for q,k; hi for v), once ----------------
__global__ __launch_bounds__(64) void wcast_kernel(
    const float* __restrict__ Wq, const float* __restrict__ bq,
    const float* __restrict__ Wk, const float* __restrict__ bk,
    const float* __restrict__ Wv, const float* __restrict__ bv,
    unsigned short* __restrict__ wfh, unsigned short* __restrict__ wfl,
    float* __restrict__ bias_ws)
{
    const int rt = blockIdx.x;
    const int lane = threadIdx.x, l15 = lane & 15, quad = lane >> 4;
    const float *Ws, *bs; int roff; float scale = 1.0f;
    if (rt < 2)      { Ws = Wq; bs = bq; roff = rt * 16;      scale = 1.44269504f; }
    else if (rt < 4) { Ws = Wk; bs = bk; roff = (rt - 2) * 16; }
    else             { Ws = Wv; bs = bv; roff = (rt - 4) * 16; }

    const float* wrow = Ws + (size_t)(roff + l15) * CCH + quad * 8;
    for (int kb = 0; kb < 8; ++kb) {
        s16x8 h, l;
        #pragma unroll
        for (int d = 0; d < 8; ++d) {
            float wv = wrow[kb * 32 + d] * scale;
            unsigned short hh = f2bf(wv);
            h[d] = (short)hh;
            l[d] = (short)f2bf(wv - bf2f(hh));
        }
        *(s16x8*)&wfh[(((size_t)rt * 8 + kb) * 64 + lane) * 8] = h;
        if (rt < 4) *(s16x8*)&wfl[(((size_t)rt * 8 + kb) * 64 + lane) * 8] = l;
    }
    if (lane < 16) bias_ws[rt * 16 + lane] = bs[roff + lane] * scale;
}

// ---------------- fused cast+projection ----------------
__global__ __launch_bounds__(256, 4) void proj_kernel(
    const float* __restrict__ x,
    const unsigned short* __restrict__ wfh, const unsigned short* __restrict__ wfl,
    const float* __restrict__ bias_ws,
    unsigned short* __restrict__ q_hi, unsigned short* __restrict__ q_lo,
    unsigned short* __restrict__ k_hi, unsigned short* __restrict__ k_lo,
    unsigned short* __restrict__ v_frag)
{
    const int t = threadIdx.x;
    const int rh = t >> 6, lane = t & 63, l15 = lane & 15, quad = lane >> 4;
    const int b = blockIdx.y;
    const int nt = blockIdx.x;

    const float* xb = x + (size_t)b * CCH * NPIX + nt * 16 + l15;
    s16x8 xh[8], xl[8];
    #pragma unroll
    for (int kb = 0; kb < 8; ++kb) {
        s16x8 vh, vl;
        #pragma unroll
        for (int d = 0; d < 8; ++d) {
            float xv = xb[(size_t)(kb * 32 + quad * 8 + d) * NPIX];
            unsigned short h = f2bf(xv);
            vh[d] = (short)h;
            vl[d] = (short)f2bf(xv - bf2f(h));
        }
        xh[kb] = vh; xl[kb] = vl;
    }

    const int n = nt * 16 + l15;
    #pragma unroll 1
    for (int tt = 0; tt < 5; ++tt) {
        const int rt = rh * 5 + tt;
        if (rt < 4) {
            f32x4 acc0 = {0.f, 0.f, 0.f, 0.f};
            f32x4 acc1 = {0.f, 0.f, 0.f, 0.f};
            #pragma unroll
            for (int kb = 0; kb < 8; ++kb) {
                s16x8 ah = *(const s16x8*)&wfh[(((size_t)rt * 8 + kb) * 64 + lane) * 8];
                s16x8 al = *(const s16x8*)&wfl[(((size_t)rt * 8 + kb) * 64 + lane) * 8];
                acc0 = __builtin_amdgcn_mfma_f32_16x16x32_bf16(ah, xh[kb], acc0, 0, 0, 0);
                acc1 = __builtin_amdgcn_mfma_f32_16x16x32_bf16(ah, xl[kb], acc1, 0, 0, 0);
                acc1 = __builtin_amdgcn_mfma_f32_16x16x32_bf16(al, xh[kb], acc1, 0, 0, 0);
            }
            #pragma unroll
            for (int rr = 0; rr < 4; ++rr) {
                const int rloc = quad * 4 + rr;
                const float val = acc0[rr] + acc1[rr] + bias_ws[rt * 16 + rloc];
                unsigned short h = f2bf(val);
                unsigned short l = f2bf(val - bf2f(h));
                if (rt < 2) {
                    const size_t a = qk_addr(b, n, rt * 16 + rloc);
                    q_hi[a] = h; q_lo[a] = l;
                } else {
                    const size_t a = qk_addr(b, n, (rt - 2) * 16 + rloc);
                    k_hi[a] = h; k_lo[a] = l;
                }
            }
        } else {
            f32x4 acc = {0.f, 0.f, 0.f, 0.f};
            #pragma unroll
            for (int kb = 0; kb < 8; ++kb) {
                s16x8 ah = *(const s16x8*)&wfh[(((size_t)rt * 8 + kb) * 64 + lane) * 8];
                acc = __builtin_amdgcn_mfma_f32_16x16x32_bf16(ah, xh[kb], acc, 0, 0, 0);
            }
            #pragma unroll
            for (int rr = 0; rr < 4; ++rr) {
                const int rloc = quad * 4 + rr;
                const float val = acc[rr] + bias_ws[rt * 16 + rloc];
                v_frag[v_addr(b, n, (rt - 4) * 16 + rloc)] = f2bf(val);
            }
        }
    }
}

// ---------------- flash attention: 64c x 32i waves, P via LDS ----------------
// 512 blocks (2/CU, same batch per CU) x 8 waves = (jh 0..1, ch 0..3).
// ALL register arrays are indexed by compile-time constants only (scratch-spill fix).
__global__ __launch_bounds__(512, 4) void attn_kernel(
    const unsigned short* __restrict__ q_hi, const unsigned short* __restrict__ q_lo,
    const unsigned short* __restrict__ k_hi, const unsigned short* __restrict__ k_lo,
    const unsigned short* __restrict__ v_frag,
    const float* __restrict__ x, float* __restrict__ out)
{
    __shared__ unsigned short p_lds[2][2][4][512];   // [jh][dbuf][frag][lane*8] = 16 KB
    __shared__ float comb[2][4][64][20];             // [jh_src][ch][lane][16(+4)] = 40 KB
    __shared__ float lds_l[2][2][16];

    const int t = threadIdx.x;
    const int w = t >> 6, lane = t & 63, l15 = lane & 15, quad = lane >> 4;
    const int jh = w >> 2, ch = w & 3;

    const int f = blockIdx.x;                 // 0..511; XCD-pair per batch
    const int xcd = f & 7;
    const int b = xcd >> 1;
    const int ib = ((xcd & 1) << 6) + (f >> 3);   // i-block 0..127 (32 pixels)

    s16x8 qfh0, qfl0, qfh1, qfl1;
    {
        const size_t qo0 = ((size_t)b * 256 + ib * 2 + 0) * 512 + (size_t)lane * 8;
        const size_t qo1 = ((size_t)b * 256 + ib * 2 + 1) * 512 + (size_t)lane * 8;
        qfh0 = *(const s16x8*)(q_hi + qo0);  qfl0 = *(const s16x8*)(q_lo + qo0);
        qfh1 = *(const s16x8*)(q_hi + qo1);  qfl1 = *(const s16x8*)(q_lo + qo1);
    }

    const s16x8 ones = { (short)0x3F80, (short)0x3F80, (short)0x3F80, (short)0x3F80,
                         (short)0x3F80, (short)0x3F80, (short)0x3F80, (short)0x3F80 };

    f32x4 acc[8];                             // [ct*2+it], constant indices only
    #pragma unroll
    for (int i = 0; i < 8; ++i) acc[i] = (f32x4){0.f, 0.f, 0.f, 0.f};
    f32x4 lacc = {0.f, 0.f, 0.f, 0.f};

    const unsigned short* khb = k_hi + (size_t)b * 131072 + (size_t)lane * 8;
    const unsigned short* klb = k_lo + (size_t)b * 131072 + (size_t)lane * 8;
    const unsigned short* vb  = v_frag + (size_t)b * 1048576 + (size_t)lane * 8;

    const int prow = ((ch & 1) << 1) + (quad >> 1);
    const int pcol = ((quad & 1) << 2);
    const int pfrag_jj = ch >> 1;

    #pragma unroll 1
    for (int j5 = 0; j5 < 32; ++j5) {
        const int jt = jh * 32 + j5;
        const int buf = j5 & 1;
        // ---- S^T quarter: K tile (jt*4+ch), 2 i-tiles x 3-term ----
        const size_t ko = (size_t)(jt * 4 + ch) * 512;
        const s16x8 kfh = *(const s16x8*)(khb + ko);
        const s16x8 kfl = *(const s16x8*)(klb + ko);
        #pragma unroll
        for (int it = 0; it < 2; ++it) {
            f32x4 a0;
            if (it == 0) {
                a0 = __builtin_amdgcn_mfma_f32_16x16x32_bf16(kfh, qfl0, (f32x4){0.f,0.f,0.f,0.f}, 0, 0, 0);
                a0 = __builtin_amdgcn_mfma_f32_16x16x32_bf16(kfl, qfh0, a0, 0, 0, 0);
                a0 = __builtin_amdgcn_mfma_f32_16x16x32_bf16(kfh, qfh0, a0, 0, 0, 0);
            } else {
                a0 = __builtin_amdgcn_mfma_f32_16x16x32_bf16(kfh, qfl1, (f32x4){0.f,0.f,0.f,0.f}, 0, 0, 0);
                a0 = __builtin_amdgcn_mfma_f32_16x16x32_bf16(kfl, qfh1, a0, 0, 0, 0);
                a0 = __builtin_amdgcn_mfma_f32_16x16x32_bf16(kfh, qfh1, a0, 0, 0, 0);
            }
            unsigned int u0 = __float_as_uint(__builtin_exp2f(a0[0])) + 0x8000u;
            unsigned int u1 = __float_as_uint(__builtin_exp2f(a0[1])) + 0x8000u;
            unsigned int u2 = __float_as_uint(__builtin_exp2f(a0[2])) + 0x8000u;
            unsigned int u3 = __float_as_uint(__builtin_exp2f(a0[3])) + 0x8000u;
            uint2 pv;
            pv.x = __builtin_amdgcn_perm(u1, u0, 0x07060302u);
            pv.y = __builtin_amdgcn_perm(u3, u2, 0x07060302u);
            *(uint2*)&p_lds[jh][buf][it * 2 + pfrag_jj][(prow * 16 + l15) * 8 + pcol] = pv;
        }
        __syncthreads();
        // ---- read 4 P B-frags into NAMED registers ----
        const s16x8 pf0 = *(const s16x8*)&p_lds[jh][buf][0][lane * 8];
        const s16x8 pf1 = *(const s16x8*)&p_lds[jh][buf][1][lane * 8];
        const s16x8 pf2 = *(const s16x8*)&p_lds[jh][buf][2][lane * 8];
        const s16x8 pf3 = *(const s16x8*)&p_lds[jh][buf][3][lane * 8];
        // ---- denominator partials: ch0 -> it0 (pf0,pf1), ch1 -> it1 (pf2,pf3) ----
        if (ch == 0) {
            lacc = __builtin_amdgcn_mfma_f32_16x16x32_bf16(ones, pf0, lacc, 0, 0, 0);
            lacc = __builtin_amdgcn_mfma_f32_16x16x32_bf16(ones, pf1, lacc, 0, 0, 0);
        } else if (ch == 1) {
            lacc = __builtin_amdgcn_mfma_f32_16x16x32_bf16(ones, pf2, lacc, 0, 0, 0);
            lacc = __builtin_amdgcn_mfma_f32_16x16x32_bf16(ones, pf3, lacc, 0, 0, 0);
        }
        // ---- PV: V quarter (4 c-tiles) x 2 i-tiles x 2 jj ----
        #pragma unroll
        for (int ct = 0; ct < 4; ++ct) {
            const size_t vo = (((size_t)jt * 16 + ch * 4 + ct) * 2) * 512;
            const s16x8 v0 = *(const s16x8*)(vb + vo);
            const s16x8 v1 = *(const s16x8*)(vb + vo + 512);
            acc[ct * 2 + 0] = __builtin_amdgcn_mfma_f32_16x16x32_bf16(v0, pf0, acc[ct * 2 + 0], 0, 0, 0);
            acc[ct * 2 + 0] = __builtin_amdgcn_mfma_f32_16x16x32_bf16(v1, pf1, acc[ct * 2 + 0], 0, 0, 0);
            acc[ct * 2 + 1] = __builtin_amdgcn_mfma_f32_16x16x32_bf16(v0, pf2, acc[ct * 2 + 1], 0, 0, 0);
            acc[ct * 2 + 1] = __builtin_amdgcn_mfma_f32_16x16x32_bf16(v1, pf3, acc[ct * 2 + 1], 0, 0, 0);
        }
    }

    // ---- epilogue (constant indices inside wave-uniform branches) ----
    if (ch < 2 && lane < 16) lds_l[jh][ch][lane] = lacc[0];
    if (jh == 0) {          // own it0; publish it1
        #pragma unroll
        for (int ct = 0; ct < 4; ++ct)
            *(f32x4*)&comb[0][ch][lane][ct * 4] = acc[ct * 2 + 1];
    } else {                // own it1; publish it0
        #pragma unroll
        for (int ct = 0; ct < 4; ++ct)
            *(f32x4*)&comb[1][ch][lane][ct * 4] = acc[ct * 2 + 0];
    }
    __syncthreads();
    const float linv = 1.f / (lds_l[0][jh][l15] + lds_l[1][jh][l15]);
    const int ibase = (ib * 2 + jh) * 16 + l15;
    #pragma unroll
    for (int ct = 0; ct < 4; ++ct) {
        f32x4 a;
        if (jh == 0) a = acc[ct * 2 + 0];
        else         a = acc[ct * 2 + 1];
        a += *(const f32x4*)&comb[1 - jh][ch][lane][ct * 4];
        #pragma unroll
        for (int rr = 0; rr < 4; ++rr) {
            const int c = ch * 64 + ct * 16 + quad * 4 + rr;
            const size_t idx = ((size_t)b * CCH + c) * NPIX + ibase;
            out[idx] = a[rr] * linv + x[idx];
        }
    }
}

extern "C" void kernel_launch(void* const* d_in, const int* in_sizes, int n_in,
                              void* d_out, int out_size, void* d_ws, size_t ws_size,
                              hipStream_t stream) {
    const float* x  = (const float*)d_in[0];
    const float* Wq = (const float*)d_in[1];
    const float* bq = (const float*)d_in[2];
    const float* Wk = (const float*)d_in[3];
    const float* bk = (const float*)d_in[4];
    const float* Wv = (const float*)d_in[5];
    const float* bv = (const float*)d_in[6];
    float* out = (float*)d_out;

    unsigned short* ws = (unsigned short*)d_ws;
    unsigned short* q_hi   = ws;                 //   524,288
    unsigned short* q_lo   = ws + 524288;        //   524,288
    unsigned short* k_hi   = ws + 1048576;       //   524,288
    unsigned short* k_lo   = ws + 1572864;       //   524,288
    unsigned short* v_frag = ws + 2097152;       // 4,194,304
    unsigned short* wfh    = ws + 6291456;       //    81,920
    unsigned short* wfl    = ws + 6373376;       //    16,384
    float*          bias_ws = (float*)(ws + 6389760);  // 320 floats

    wcast_kernel<<<20, 64, 0, stream>>>(Wq, bq, Wk, bk, Wv, bv, wfh, wfl, bias_ws);
    proj_kernel<<<dim3(256, BATCH), 256, 0, stream>>>(x, wfh, wfl, bias_ws,
                                                      q_hi, q_lo, k_hi, k_lo, v_frag);
    attn_kernel<<<512, 512, 0, stream>>>(q_hi, q_lo, k_hi, k_lo, v_frag, x, out);
}